// Round 7
// baseline (1434.865 us; speedup 1.0000x reference)
//
#include <hip/hip_runtime.h>
#include <cstdint>
#include <cstddef>

#define SEQ 8192
#define THREADS 256
#define CHUNK 32
#define THR_F 200.0f
#define EPS_F 1e-7f

// Workspace accumulator layout (doubles):
// 0 err2, 1 msum, 2 bce(base+corr), 3 wExtra, 4 mono, 5 vp, 6 smooth, 7 vt,
// 8 phys, 9 npos, 10 bound, 11 any1
#define N_ACC 12

// Single-pass, LDS-free (5KB junction buffer only) chunk-contiguous design.
// Thread t owns elements [32t, 32t+32) of its row; neighbor terms computed
// via in-register carries; the 255 chunk junctions exchanged through LDS.
__global__ __launch_bounds__(THREADS, 4) void physloss_row_kernel(
    const float* __restrict__ pred,
    const float* __restrict__ targ,
    const float* __restrict__ bprob,
    const int*   __restrict__ mask,
    const float* __restrict__ voltage,
    const float* __restrict__ thickness,
    double* __restrict__ acc)
{
    __shared__ float sj[THREADS][5];   // f0,f1,m0,m1 (+pad: stride 5 -> conflict-free)
    __shared__ float red[4][10];
    __shared__ int redLast[4];

    const int row = blockIdx.x;
    const int t = threadIdx.x;
    const size_t base = (size_t)row * SEQ;
    const int c0 = t * CHUNK;

    const float4* p4 = (const float4*)(pred + base) + t * (CHUNK / 4);
    const float4* t4 = (const float4*)(targ + base) + t * (CHUNK / 4);
    const float4* b4 = (const float4*)(bprob + base) + t * (CHUNK / 4);
    const int4*   m4 = (const int4*)(mask + base) + t * (CHUNK / 4);

    float err2 = 0.f, msum = 0.f, bce = 0.f, bound = 0.f;
    float mono = 0.f, vp = 0.f, smooth = 0.f, vt = 0.f, vdiff = 0.f, mfirst = 0.f;
    int lastIdx = -1;
    float pm1 = 0.f, pm2 = 0.f, mm1 = 0.f, mm2 = 0.f;  // carries: elements i-1, i-2

    #pragma unroll
    for (int k = 0; k < CHUNK / 4; ++k) {
        float4 p  = p4[k];
        float4 tv = t4[k];
        float4 bv = b4[k];
        int4   mv = m4[k];

        float pe[4]  = {p.x, p.y, p.z, p.w};
        float te[4]  = {tv.x, tv.y, tv.z, tv.w};
        float be[4]  = {bv.x, bv.y, bv.z, bv.w};
        float me_[4] = {mv.x ? 1.f : 0.f, mv.y ? 1.f : 0.f,
                        mv.z ? 1.f : 0.f, mv.w ? 1.f : 0.f};

        if (k == 0) {  // publish first two elements for the left neighbor's junction
            sj[t][0] = pe[0]; sj[t][1] = pe[1];
            sj[t][2] = me_[0]; sj[t][3] = me_[1];
        }

        #pragma unroll
        for (int e = 0; e < 4; ++e) {
            int i = 4 * k + e;          // chunk-local index 0..31
            float m = me_[e];
            float d = pe[e] - te[e];
            err2 += d * d * m;
            msum += m;
            bound += fmaxf(pe[e] - THR_F, 0.f);
            float pc = fminf(fmaxf(be[e], EPS_F), 1.f - EPS_F);
            bce += m * (-log1pf(-pc));
            if (m != 0.f) lastIdx = c0 + i;
            if (i >= 1) {               // pair with left index (i-1) -> ours
                float dd = pe[e] - pm1;
                float mm = mm1 * m;
                mono += fmaxf(-dd, 0.f) * mm;
                vp += mm;
                vdiff += dd * mm1;      // reference: (p[l+1]-p[l]) * m[l]
                mfirst += mm1;
                if (i >= 2) {           // triple with left index (i-2) -> ours
                    float t3 = mm * mm2;
                    smooth += fabsf(pe[e] - 2.f * pm1 + pm2) * t3;
                    vt += t3;
                }
            }
            pm2 = pm1; mm2 = mm1;
            pm1 = pe[e]; mm1 = m;
        }
    }

    __syncthreads();

    // Junction terms (pairs/triples whose left index is c0+30/c0+31).
    // t==255: those left indices exceed S-2 / S-3 -> correctly skipped.
    if (t < THREADS - 1) {
        float j0  = sj[t + 1][0], j1  = sj[t + 1][1];
        float jm0 = sj[t + 1][2], jm1 = sj[t + 1][3];
        // pair left = c0+31: (pm1, j0)
        float dd = j0 - pm1;
        float mm = mm1 * jm0;
        mono += fmaxf(-dd, 0.f) * mm;
        vp += mm;
        vdiff += dd * mm1;
        mfirst += mm1;
        // triple left = c0+30: (pm2, pm1, j0)
        float t3a = mm2 * mm1 * jm0;
        smooth += fabsf(j0 - 2.f * pm1 + pm2) * t3a;
        vt += t3a;
        // triple left = c0+31: (pm1, j0, j1)
        float t3b = mm1 * jm0 * jm1;
        smooth += fabsf(j1 - 2.f * j0 + pm1) * t3b;
        vt += t3b;
    }

    // ---- Wave reduce (64-lane) then cross-wave via LDS ----
    float v[10] = {err2, msum, bce, bound, mono, vp, smooth, vt, vdiff, mfirst};
    #pragma unroll
    for (int off = 32; off > 0; off >>= 1) {
        #pragma unroll
        for (int k = 0; k < 10; ++k) v[k] += __shfl_down(v[k], off, 64);
        int o = __shfl_down(lastIdx, off, 64);
        lastIdx = lastIdx > o ? lastIdx : o;
    }
    int wave = t >> 6, lane = t & 63;
    if (lane == 0) {
        #pragma unroll
        for (int k = 0; k < 10; ++k) red[wave][k] = v[k];
        redLast[wave] = lastIdx;
    }
    __syncthreads();

    if (t == 0) {
        float s[10];
        #pragma unroll
        for (int k = 0; k < 10; ++k) s[k] = red[0][k] + red[1][k] + red[2][k] + red[3][k];
        int last = redLast[0];
        #pragma unroll
        for (int w = 1; w < 4; ++w) last = last > redLast[w] ? last : redLast[w];

        // breakdown-target correction at the last valid index
        float bceCorr = 0.f, wExtra = 0.f;
        if (last >= 0) {
            float tl = targ[base + last];
            bool cond = (last < SEQ - 1) || (tl >= 190.0f);  // THR*0.95 == 190.0f in f32
            if (cond) {
                float pl = fminf(fmaxf(bprob[base + last], EPS_F), 1.0f - EPS_F);
                // base already added -log1p(-pl)*1 (mask=1 at last); replace with 5*(-log(pl))
                bceCorr = -5.0f * logf(pl) + log1pf(-pl);
                wExtra = 4.0f;
            }
        }

        float m0row = sj[0][2];                          // mask of column 0
        float any1 = (s[1] - m0row) > 0.f ? 1.f : 0.f;   // any valid in cols 1..S-1

        // physics per-row term
        float physv = 0.f, nposv = 0.f;
        float avg = s[8] / fmaxf(s[9], 1.f);
        if (avg > 0.f) {
            float lr = logf(fmaxf(avg, 1e-8f));
            float ef = fabsf(voltage[row]) / thickness[row] * 1e-7f;
            float ff = expf(0.1f * ef);
            float lff = logf(fmaxf(ff, 1e-8f));
            float dd = lr - lff;
            physv = dd * dd;
            nposv = 1.f;
        }

        atomicAdd(&acc[0],  (double)s[0]);             // err2
        atomicAdd(&acc[1],  (double)s[1]);             // msum
        atomicAdd(&acc[2],  (double)(s[2] + bceCorr)); // bce
        atomicAdd(&acc[3],  (double)wExtra);           // extra weight (4 per bt row)
        atomicAdd(&acc[4],  (double)s[4]);             // mono
        atomicAdd(&acc[5],  (double)s[5]);             // vp
        atomicAdd(&acc[6],  (double)s[6]);             // smooth
        atomicAdd(&acc[7],  (double)s[7]);             // vt
        atomicAdd(&acc[8],  (double)physv);            // phys
        atomicAdd(&acc[9],  (double)nposv);            // npos
        atomicAdd(&acc[10], (double)s[3]);             // bound
        atomicAdd(&acc[11], (double)any1);             // any1
    }
}

__global__ void physloss_finalize_kernel(const double* __restrict__ acc,
                                         float* __restrict__ out,
                                         double inv_count_scale /* = 1/(B*S) */)
{
    if (threadIdx.x == 0 && blockIdx.x == 0) {
        double err2 = acc[0], msum = acc[1], bce = acc[2], wX = acc[3];
        double mono = acc[4], vp = acc[5], sm = acc[6], vt = acc[7];
        double ph = acc[8], np = acc[9], bd = acc[10], a1 = acc[11];

        bool any = msum > 0.0;
        float predL = any ? (float)(err2 / fmax(msum, 1.0)) : 0.f;
        double wsum = msum + wX;
        float bdL = any ? (float)(bce / fmax(wsum, 1.0)) : 0.f;
        float monoL = (vp > 0.0) ? (float)(mono / fmax(vp, 1.0)) : 0.f;
        float smL = (vt > 0.0) ? (float)(sm / fmax(vt, 1.0)) : 0.f;
        float phL = (a1 > 0.0 && np > 0.0) ? (float)(ph / fmax(np, 1.0)) : 0.f;
        float boL = (float)(bd * inv_count_scale) * 0.1f;

        float total = 1.0f * predL + 0.5f * bdL + 0.2f * monoL
                    + 0.1f * smL + 0.3f * phL + boL;

        out[0] = predL; out[1] = bdL; out[2] = monoL; out[3] = smL;
        out[4] = phL;   out[5] = boL; out[6] = total;
    }
}

extern "C" void kernel_launch(void* const* d_in, const int* in_sizes, int n_in,
                              void* d_out, int out_size, void* d_ws, size_t ws_size,
                              hipStream_t stream) {
    const float* pred  = (const float*)d_in[0];
    const float* targ  = (const float*)d_in[1];
    const float* bprob = (const float*)d_in[2];
    const int*   mask  = (const int*)d_in[3];    // bool -> int32 (verified: absmax 0.0)
    const float* volt  = (const float*)d_in[4];
    const float* thick = (const float*)d_in[5];

    const int B = in_sizes[4];                   // voltage is [B]
    double* acc = (double*)d_ws;

    hipMemsetAsync(acc, 0, N_ACC * sizeof(double), stream);
    physloss_row_kernel<<<B, THREADS, 0, stream>>>(pred, targ, bprob, mask,
                                                   volt, thick, acc);
    double inv_cnt = 1.0 / ((double)B * (double)SEQ);
    physloss_finalize_kernel<<<1, 64, 0, stream>>>(acc, (float*)d_out, inv_cnt);
}

// Round 13
// 868.477 us; speedup vs baseline: 1.6522x; 1.6522x over previous
//
#include <hip/hip_runtime.h>
#include <cstdint>
#include <cstddef>

#define SEQ 8192
#define THREADS 256
#define NJ (SEQ / 4 / THREADS)   // 8 float4 iterations
#define THR_F 200.0f
#define EPS_F 1e-7f

// Workspace accumulator layout (doubles):
// 0 err2, 1 msum, 2 bce(base+corr), 3 wExtra, 4 mono, 5 vp, 6 smooth, 7 vt,
// 8 phys, 9 npos, 10 bound, 11 any1
#define N_ACC 12

// Interleaved coalesced float4 loads (round-5 pattern, FETCH-optimal) +
// single-pass in-register neighbor terms (round-7 structure). Per-quad
// junctions via a double-buffered 256-entry LDS head table (1 barrier/j);
// the t=255 <-> next-j t=0 junction is deferred one iteration.
__global__ __launch_bounds__(THREADS, 8) void physloss_row_kernel(
    const float* __restrict__ pred,
    const float* __restrict__ targ,
    const float* __restrict__ bprob,
    const int*   __restrict__ mask,
    const float* __restrict__ voltage,
    const float* __restrict__ thickness,
    double* __restrict__ acc)
{
    __shared__ float4 sj[2][THREADS];   // (x, y, mx, my) head of each thread's quad
    __shared__ float red[4][10];
    __shared__ int redLast[4];

    const int row = blockIdx.x;
    const int t = threadIdx.x;
    const size_t base = (size_t)row * SEQ;

    const float4* p4 = (const float4*)(pred + base);
    const float4* t4 = (const float4*)(targ + base);
    const float4* b4 = (const float4*)(bprob + base);
    const int4*   m4 = (const int4*)(mask + base);

    float err2 = 0.f, msum = 0.f, bce = 0.f, bound = 0.f;
    float mono = 0.f, vp = 0.f, smooth = 0.f, vt = 0.f, vdiff = 0.f, mfirst = 0.f;
    int lastIdx = -1;
    float m0row = 0.f;
    float tp2 = 0.f, tp3 = 0.f, tm2 = 0.f, tm3 = 0.f;  // t==255's prev-j tail

    #pragma unroll
    for (int j = 0; j < NJ; ++j) {
        const int i4 = j * THREADS + t;       // coalesced: lane-consecutive
        float4 p  = p4[i4];
        float4 tv = t4[i4];
        float4 bv = b4[i4];
        int4   mv = m4[i4];

        const float m0 = mv.x ? 1.f : 0.f, m1 = mv.y ? 1.f : 0.f;
        const float m2 = mv.z ? 1.f : 0.f, m3 = mv.w ? 1.f : 0.f;

        sj[j & 1][t] = make_float4(p.x, p.y, m0, m1);   // publish head
        if (j == 0 && t == 0) m0row = m0;

        // ---- element-local terms ----
        {
            float d0 = p.x - tv.x, d1 = p.y - tv.y, d2 = p.z - tv.z, d3 = p.w - tv.w;
            err2 += d0*d0*m0 + d1*d1*m1 + d2*d2*m2 + d3*d3*m3;
            msum += m0 + m1 + m2 + m3;
            bound += fmaxf(p.x - THR_F, 0.f) + fmaxf(p.y - THR_F, 0.f)
                   + fmaxf(p.z - THR_F, 0.f) + fmaxf(p.w - THR_F, 0.f);
            float c0 = fminf(fmaxf(bv.x, EPS_F), 1.f - EPS_F);
            float c1 = fminf(fmaxf(bv.y, EPS_F), 1.f - EPS_F);
            float c2 = fminf(fmaxf(bv.z, EPS_F), 1.f - EPS_F);
            float c3 = fminf(fmaxf(bv.w, EPS_F), 1.f - EPS_F);
            bce += m0 * (-log1pf(-c0)) + m1 * (-log1pf(-c1))
                 + m2 * (-log1pf(-c2)) + m3 * (-log1pf(-c3));
            int g = 4 * i4;
            lastIdx = (m3 != 0.f) ? g + 3 : (m2 != 0.f) ? g + 2
                    : (m1 != 0.f) ? g + 1 : (m0 != 0.f) ? g : lastIdx;
        }

        // ---- in-quad neighbor terms (lefts g0,g1,g2) ----
        {
            float d01 = p.y - p.x, d12 = p.z - p.y, d23 = p.w - p.z;
            float w01 = m0 * m1, w12 = m1 * m2, w23 = m2 * m3;
            mono += fmaxf(-d01, 0.f) * w01 + fmaxf(-d12, 0.f) * w12
                  + fmaxf(-d23, 0.f) * w23;
            vp += w01 + w12 + w23;
            vdiff += d01 * m0 + d12 * m1 + d23 * m2;
            mfirst += m0 + m1 + m2;
            float t3a = w01 * m2;  // left g0
            smooth += fabsf(p.z - 2.f * p.y + p.x) * t3a;
            float t3b = w12 * m3;  // left g1
            smooth += fabsf(p.w - 2.f * p.z + p.y) * t3b;
            vt += t3a + t3b;
        }

        __syncthreads();

        // ---- deferred j-boundary junction: t==255's (j-1) tail vs this j's t=0 head
        if (t == THREADS - 1 && j > 0) {
            float4 h = sj[j & 1][0];
            float dd = h.x - tp3;
            float mm = tm3 * h.z;
            mono += fmaxf(-dd, 0.f) * mm;  vp += mm;
            vdiff += dd * tm3;             mfirst += tm3;
            float a = tm2 * tm3 * h.z;
            smooth += fabsf(h.x - 2.f * tp3 + tp2) * a;
            float b = tm3 * h.z * h.w;
            smooth += fabsf(h.y - 2.f * h.x + tp3) * b;
            vt += a + b;
        }
        // ---- same-j quad junction (lefts g2,g3) with right neighbor's head
        if (t < THREADS - 1) {
            float4 h = sj[j & 1][t + 1];
            float dd = h.x - p.w;
            float mm = m3 * h.z;
            mono += fmaxf(-dd, 0.f) * mm;  vp += mm;
            vdiff += dd * m3;              mfirst += m3;
            float a = m2 * m3 * h.z;
            smooth += fabsf(h.x - 2.f * p.w + p.z) * a;
            float b = m3 * h.z * h.w;
            smooth += fabsf(h.y - 2.f * h.x + p.w) * b;
            vt += a + b;
        }
        tp2 = p.z; tp3 = p.w; tm2 = m2; tm3 = m3;
        // t==255, j==NJ-1 tail: lefts 8190/8191 have no right neighbor -> skip (correct)
    }

    // ---- Wave reduce (64-lane) then cross-wave via LDS ----
    float v[10] = {err2, msum, bce, bound, mono, vp, smooth, vt, vdiff, mfirst};
    #pragma unroll
    for (int off = 32; off > 0; off >>= 1) {
        #pragma unroll
        for (int k = 0; k < 10; ++k) v[k] += __shfl_down(v[k], off, 64);
        int o = __shfl_down(lastIdx, off, 64);
        lastIdx = lastIdx > o ? lastIdx : o;
    }
    int wave = t >> 6, lane = t & 63;
    if (lane == 0) {
        #pragma unroll
        for (int k = 0; k < 10; ++k) red[wave][k] = v[k];
        redLast[wave] = lastIdx;
    }
    __syncthreads();

    if (t == 0) {
        float s[10];
        #pragma unroll
        for (int k = 0; k < 10; ++k) s[k] = red[0][k] + red[1][k] + red[2][k] + red[3][k];
        int last = redLast[0];
        #pragma unroll
        for (int w = 1; w < 4; ++w) last = last > redLast[w] ? last : redLast[w];

        // breakdown-target correction at the last valid index
        float bceCorr = 0.f, wExtra = 0.f;
        if (last >= 0) {
            float tl = targ[base + last];
            bool cond = (last < SEQ - 1) || (tl >= 190.0f);  // THR*0.95 == 190.0f in f32
            if (cond) {
                float pl = fminf(fmaxf(bprob[base + last], EPS_F), 1.0f - EPS_F);
                // base added m*(-log1p(-pl)); replace with 5*(-log(pl))
                bceCorr = -5.0f * logf(pl) + log1pf(-pl);
                wExtra = 4.0f;
            }
        }

        float any1 = (s[1] - m0row) > 0.f ? 1.f : 0.f;   // any valid in cols 1..S-1

        // physics per-row term
        float physv = 0.f, nposv = 0.f;
        float avg = s[8] / fmaxf(s[9], 1.f);
        if (avg > 0.f) {
            float lr = logf(fmaxf(avg, 1e-8f));
            float ef = fabsf(voltage[row]) / thickness[row] * 1e-7f;
            float ff = expf(0.1f * ef);
            float lff = logf(fmaxf(ff, 1e-8f));
            float dd = lr - lff;
            physv = dd * dd;
            nposv = 1.f;
        }

        atomicAdd(&acc[0],  (double)s[0]);             // err2
        atomicAdd(&acc[1],  (double)s[1]);             // msum
        atomicAdd(&acc[2],  (double)(s[2] + bceCorr)); // bce
        atomicAdd(&acc[3],  (double)wExtra);           // extra weight (4 per bt row)
        atomicAdd(&acc[4],  (double)s[4]);             // mono
        atomicAdd(&acc[5],  (double)s[5]);             // vp
        atomicAdd(&acc[6],  (double)s[6]);             // smooth
        atomicAdd(&acc[7],  (double)s[7]);             // vt
        atomicAdd(&acc[8],  (double)physv);            // phys
        atomicAdd(&acc[9],  (double)nposv);            // npos
        atomicAdd(&acc[10], (double)s[3]);             // bound
        atomicAdd(&acc[11], (double)any1);             // any1
    }
}

__global__ void physloss_finalize_kernel(const double* __restrict__ acc,
                                         float* __restrict__ out,
                                         double inv_count_scale /* = 1/(B*S) */)
{
    if (threadIdx.x == 0 && blockIdx.x == 0) {
        double err2 = acc[0], msum = acc[1], bce = acc[2], wX = acc[3];
        double mono = acc[4], vp = acc[5], sm = acc[6], vt = acc[7];
        double ph = acc[8], np = acc[9], bd = acc[10], a1 = acc[11];

        bool any = msum > 0.0;
        float predL = any ? (float)(err2 / fmax(msum, 1.0)) : 0.f;
        double wsum = msum + wX;
        float bdL = any ? (float)(bce / fmax(wsum, 1.0)) : 0.f;
        float monoL = (vp > 0.0) ? (float)(mono / fmax(vp, 1.0)) : 0.f;
        float smL = (vt > 0.0) ? (float)(sm / fmax(vt, 1.0)) : 0.f;
        float phL = (a1 > 0.0 && np > 0.0) ? (float)(ph / fmax(np, 1.0)) : 0.f;
        float boL = (float)(bd * inv_count_scale) * 0.1f;

        float total = 1.0f * predL + 0.5f * bdL + 0.2f * monoL
                    + 0.1f * smL + 0.3f * phL + boL;

        out[0] = predL; out[1] = bdL; out[2] = monoL; out[3] = smL;
        out[4] = phL;   out[5] = boL; out[6] = total;
    }
}

extern "C" void kernel_launch(void* const* d_in, const int* in_sizes, int n_in,
                              void* d_out, int out_size, void* d_ws, size_t ws_size,
                              hipStream_t stream) {
    const float* pred  = (const float*)d_in[0];
    const float* targ  = (const float*)d_in[1];
    const float* bprob = (const float*)d_in[2];
    const int*   mask  = (const int*)d_in[3];    // bool -> int32 (verified: absmax 0.0)
    const float* volt  = (const float*)d_in[4];
    const float* thick = (const float*)d_in[5];

    const int B = in_sizes[4];                   // voltage is [B]
    double* acc = (double*)d_ws;

    hipMemsetAsync(acc, 0, N_ACC * sizeof(double), stream);
    physloss_row_kernel<<<B, THREADS, 0, stream>>>(pred, targ, bprob, mask,
                                                   volt, thick, acc);
    double inv_cnt = 1.0 / ((double)B * (double)SEQ);
    physloss_finalize_kernel<<<1, 64, 0, stream>>>(acc, (float*)d_out, inv_cnt);
}